// Round 8
// baseline (878.323 us; speedup 1.0000x reference)
//
#include <hip/hip_runtime.h>
#include <stdint.h>

// ---- filter / neuron constants (double, matching the Python reference) ----
#define EMD 0.8824969025845955      // exp(-1/8)
#define ESD 0.6065306597126334      // exp(-1/2)
#define A1C ((float)(EMD + ESD))                    // y[t-1] coeff
#define A2C ((float)(-(EMD * ESD)))                 // y[t-2] coeff
#define BC  ((float)((8.0 / 6.0) * (EMD - ESD)))    // x[t] coeff (ETA=8/6)
#define EMF ((float)EMD)                            // reset decay

// B=64, T=300. Layers: 300 -> 500 -> 200 -> 500 -> 300.
//
// Exactness contract (absmax 0.0, rounds 1-7): reference currents are a
// SEQUENTIAL ascending-i fp32 fold of W[o,i]*s[i]; spikes are exactly 0/1.
// Skipping s==0 terms is bitwise-neutral; adds happen in ascending-i order.
// Pad indices read an all-zero LDS row: acc + (+0.0) is bitwise-identity
// (acc can never be -0: it starts at +0 and +0+(+/-0)=+0 in RN).

// ---------------------------------------------------------------------------
// Generic batched transpose: src [Bt][R][C] -> dst [Bt][C][R]
// ---------------------------------------------------------------------------
__global__ __launch_bounds__(256) void transpose_rc(
    const float* __restrict__ src, float* __restrict__ dst, int R, int C)
{
    __shared__ float tile[32][33];
    const int c0 = blockIdx.x * 32;
    const int r0 = blockIdx.y * 32;
    const int b  = blockIdx.z;
    const float* S = src + (size_t)b * R * C;
    float* D = dst + (size_t)b * R * C;
    const int tx = threadIdx.x;      // 0..31
    const int ty = threadIdx.y;      // 0..7
#pragma unroll
    for (int s = 0; s < 4; s++) {
        const int r = r0 + ty + 8 * s;
        const int c = c0 + tx;
        if (r < R && c < C) tile[ty + 8 * s][tx] = S[(size_t)r * C + c];
    }
    __syncthreads();
#pragma unroll
    for (int s = 0; s < 4; s++) {
        const int c = c0 + ty + 8 * s;
        const int r = r0 + tx;
        if (c < C && r < R) D[(size_t)c * R + r] = tile[tx][ty + 8 * s];
    }
}

// ---------------------------------------------------------------------------
// build_idx: per (b,t,kchunk of 32) pack ascending set-bit indices (+1) into
// 8 u32 (4 per word, zero-padded) + a group count (ceil(n/4), u8).
// One wave per (b,t); lanes 0..31 handle chunk kc2, lanes 32..63 chunk kc2+1.
// cnt8 layout: [kc][b][320] (t-padded, 32B-aligned windows)
// pk32 layout: [kc][b][300][8]
// ---------------------------------------------------------------------------
__global__ __launch_bounds__(256) void build_idx(
    const float* __restrict__ Sp, uint8_t* __restrict__ cnt8,
    uint32_t* __restrict__ pk32, int K, int nkc)
{
    const int tid  = threadIdx.x;
    const int wv   = tid >> 6;
    const int lane = tid & 63;
    const int b    = blockIdx.y;
    const int t    = blockIdx.x * 4 + wv;          // grid.x = 75 -> t < 300
    const float* row = Sp + ((size_t)b * 300 + t) * K;

    for (int kc2 = 0; kc2 < nkc; kc2 += 2) {
        const int kc = kc2 + (lane >> 5);
        const int k  = kc * 32 + (lane & 31);
        const float s = (kc < nkc && k < K) ? row[k] : 0.0f;
        const unsigned long long bal = __ballot(s != 0.0f);
#pragma unroll
        for (int h = 0; h < 2; h++) {
            const int kcc = kc2 + h;
            if (kcc >= nkc) break;
            uint32_t m = (uint32_t)(bal >> (32 * h));
            const int n = __popc(m);
            uint32_t words[8];
#pragma unroll
            for (int w = 0; w < 8; w++) {
                uint32_t acc = 0;
#pragma unroll
                for (int s2 = 0; s2 < 4; s2++) {
                    const uint32_t j1 = (uint32_t)__ffs((int)m);  // 1..32, 0 if none
                    acc |= j1 << (s2 * 8);
                    m &= m - 1;                                   // 0 stays 0
                }
                words[w] = acc;
            }
            if (lane == 0) {
                cnt8[((size_t)kcc * 64 + b) * 320 + t] = (uint8_t)((n + 3) >> 2);
                uint4* dst = (uint4*)&pk32[(((size_t)kcc * 64 + b) * 300 + t) * 8];
                dst[0] = make_uint4(words[0], words[1], words[2], words[3]);
                dst[1] = make_uint4(words[4], words[5], words[6], words[7]);
            }
        }
    }
}

// ---------------------------------------------------------------------------
// spmm_idx: C[b,t,o] = sum_{i in idx(b,t)} Wt[i,o]   (time-major, [B,T,O])
// Block: 256 thr (4 waves). Lane covers 4 o's (float4 / ds_read_b128).
// o-chunk 256, t-chunk 4*RPW (RPW t-rows per wave). K chunked at 32 rows in
// LDS (+ zero row 0 for pads); weights register-prefetched one chunk ahead.
// Indices/counts are wave-uniform -> scalar loads; no ballot/ctz in hot loop.
// ---------------------------------------------------------------------------
#define KG  32
#define OCN 256

template <int RPW>
__global__ __launch_bounds__(256) void spmm_idx(
    const float* __restrict__ Wt, float* __restrict__ C,
    const uint8_t* __restrict__ cnt8, const uint32_t* __restrict__ pk32,
    int K, int O, int nkc)
{
    __shared__ float Wls[(KG + 1) * OCN];   // row 0 = zeros; 33 KB
    const int tid  = threadIdx.x;
    const int lane = tid & 63;
    const int wvs  = __builtin_amdgcn_readfirstlane(tid >> 6);  // wave id, scalar
    const int oc   = blockIdx.x * OCN;
    const int t0   = blockIdx.y * (4 * RPW);
    const int b    = blockIdx.z;

    Wls[tid] = 0.0f;                        // zero row 0 (256 floats)

    const int scol  = lane * 4;             // 0..252
    const int srow0 = tid >> 6;             // 0..3

    float4 wpf[8];
#define LOADW(kc)                                                              \
    {                                                                          \
        const int kb_ = (kc) * KG;                                             \
        _Pragma("unroll")                                                      \
        for (int r = 0; r < 8; r++) {                                          \
            const int k = kb_ + srow0 + r * 4;                                 \
            float4 w = make_float4(0.f, 0.f, 0.f, 0.f);                        \
            if (k < K && oc + scol + 3 < O)                                    \
                w = *reinterpret_cast<const float4*>(&Wt[(size_t)k * O + oc + scol]); \
            wpf[r] = w;                                                        \
        }                                                                      \
    }
#define STOREW()                                                               \
    {                                                                          \
        _Pragma("unroll")                                                      \
        for (int r = 0; r < 8; r++)                                            \
            *reinterpret_cast<float4*>(&Wls[(size_t)(srow0 + r * 4 + 1) * OCN + scol]) = wpf[r]; \
    }

    float4 acc[RPW];
#pragma unroll
    for (int u = 0; u < RPW; u++) acc[u] = make_float4(0.f, 0.f, 0.f, 0.f);

    LOADW(0)
    STOREW()
    __syncthreads();

    const float* lrow = Wls + lane * 4;     // + idx*256 floats selects the row

    for (int kc = 0; kc < nkc; kc++) {
        if (kc + 1 < nkc) LOADW(kc + 1)     // overlaps the index loops below
        const uint32_t* c32 =
            (const uint32_t*)(cnt8 + ((size_t)kc * 64 + b) * 320 + t0);
        const uint32_t* pbase = pk32 + ((size_t)kc * 64 + b) * 300 * 8;
#pragma unroll
        for (int u = 0; u < RPW; u++) {
            const int ts = t0 + u * 4 + wvs;
            int ng = (int)((c32[u] >> (wvs * 8)) & 0xffu);
            if (ts >= 300) ng = 0;          // tail t-chunk: poison guard
            const uint32_t* prow = pbase + (size_t)ts * 8;
            float4 a = acc[u];
            for (int g = 0; g < ng; g++) {
                const uint32_t pw = prow[g];
                const int f0 = (int)((pw      ) & 0xffu) << 8;
                const int f1 = (int)((pw >> 8) & 0xffu) << 8;
                const int f2 = (int)((pw >> 16) & 0xffu) << 8;
                const int f3 = (int)((pw >> 24)        ) << 8;
                const float4 w0 = *reinterpret_cast<const float4*>(lrow + f0);
                const float4 w1 = *reinterpret_cast<const float4*>(lrow + f1);
                const float4 w2 = *reinterpret_cast<const float4*>(lrow + f2);
                const float4 w3 = *reinterpret_cast<const float4*>(lrow + f3);
                a.x += w0.x; a.y += w0.y; a.z += w0.z; a.w += w0.w;
                a.x += w1.x; a.y += w1.y; a.z += w1.z; a.w += w1.w;
                a.x += w2.x; a.y += w2.y; a.z += w2.z; a.w += w2.w;
                a.x += w3.x; a.y += w3.y; a.z += w3.z; a.w += w3.w;
            }
            acc[u] = a;
        }
        if (kc + 1 < nkc) {
            __syncthreads();
            STOREW()
            __syncthreads();
        }
    }

    float* Cb = C + (size_t)b * 300 * O;
#pragma unroll
    for (int u = 0; u < RPW; u++) {
        const int t = t0 + u * 4 + wvs;
        const int o = oc + lane * 4;
        if (t < 300 && o + 3 < O)           // O%4==0 -> all-or-nothing
            *reinterpret_cast<float4*>(&Cb[(size_t)t * O + o]) = acc[u];
    }
}

// ---------------------------------------------------------------------------
// LIF in time-major layout, in-place: C[b,t,o] currents -> spikes.
// One thread per (b,o); strided column walk, 8-deep unrolled prefetch ring.
// ---------------------------------------------------------------------------
#define LIF_STEP_S(xval, sval)                                                 \
    {                                                                          \
        const float y = A1 * y1 + A2 * y2 + Bc * (xval); y2 = y1; y1 = y;      \
        const float v = y + bi + r;                                            \
        sval = (v >= 1.0f) ? 1.0f : 0.0f;                                      \
        r = r * EMF - sval;                                                    \
    }

__global__ __launch_bounds__(64) void lif_t(
    float* __restrict__ C, const float* __restrict__ bias,
    const float* __restrict__ a1p, const float* __restrict__ a2p,
    const float* __restrict__ bp, int O)
{
    const int o = blockIdx.x * 64 + threadIdx.x;
    const int b = blockIdx.y;
    if (o >= O) return;
    const float A1 = a1p[0], A2 = a2p[0], Bc = bp[0];
    const float bi = bias[o];
    float* col = C + (size_t)b * 300 * O + o;

    float pf[8];
#pragma unroll
    for (int u = 0; u < 8; u++) pf[u] = col[(size_t)u * O];

    float y1 = 0.f, y2 = 0.f, r = 0.f;
    for (int blk = 0; blk < 37; blk++) {       // t = 0..295
#pragma unroll
        for (int u = 0; u < 8; u++) {
            const int t = blk * 8 + u;
            const float x = pf[u];
            if (t + 8 < 300) pf[u] = col[(size_t)(t + 8) * O];
            float s;
            LIF_STEP_S(x, s)
            col[(size_t)t * O] = s;
        }
    }
#pragma unroll
    for (int u = 0; u < 4; u++) {              // t = 296..299
        const float x = pf[u];
        float s;
        LIF_STEP_S(x, s)
        col[(size_t)(296 + u) * O] = s;
    }
}

// ---------------------------------------------------------------------------
// Layer-4 LIF + fixed output dual-exp IIR. C: currents->spikes (in place),
// F: filtered output. Both [B,T,O], O=300.
// ---------------------------------------------------------------------------
__global__ __launch_bounds__(64) void lif4_t(
    float* __restrict__ C, float* __restrict__ F,
    const float* __restrict__ bias,
    const float* __restrict__ a1p, const float* __restrict__ a2p,
    const float* __restrict__ bp, int O)
{
    const int o = blockIdx.x * 64 + threadIdx.x;
    const int b = blockIdx.y;
    if (o >= O) return;
    const float A1 = a1p[0], A2 = a2p[0], Bc = bp[0];
    const float bi = bias[o];
    float* col  = C + (size_t)b * 300 * O + o;
    float* fcol = F + (size_t)b * 300 * O + o;

    float pf[8];
#pragma unroll
    for (int u = 0; u < 8; u++) pf[u] = col[(size_t)u * O];

    float y1 = 0.f, y2 = 0.f, r = 0.f;
    float z1 = 0.f, z2 = 0.f;
    for (int blk = 0; blk < 37; blk++) {
#pragma unroll
        for (int u = 0; u < 8; u++) {
            const int t = blk * 8 + u;
            const float x = pf[u];
            if (t + 8 < 300) pf[u] = col[(size_t)(t + 8) * O];
            float s;
            LIF_STEP_S(x, s)
            const float z = A1C * z1 + A2C * z2 + BC * s; z2 = z1; z1 = z;
            col[(size_t)t * O]  = s;
            fcol[(size_t)t * O] = z;
        }
    }
#pragma unroll
    for (int u = 0; u < 4; u++) {
        const int t = 296 + u;
        const float x = pf[u];
        float s;
        LIF_STEP_S(x, s)
        const float z = A1C * z1 + A2C * z2 + BC * s; z2 = z1; z1 = z;
        col[(size_t)t * O]  = s;
        fcol[(size_t)t * O] = z;
    }
}

// ---------------------------------------------------------------------------
extern "C" void kernel_launch(void* const* d_in, const int* in_sizes, int n_in,
                              void* d_out, int out_size, void* d_ws, size_t ws_size,
                              hipStream_t stream)
{
    const float* inputs = (const float*)d_in[0];           // [64,300,300] binary
    const float* a1_1 = (const float*)d_in[1];
    const float* a2_1 = (const float*)d_in[2];
    const float* b_1  = (const float*)d_in[3];
    const float* W1   = (const float*)d_in[4];             // [500,300]
    const float* bias1= (const float*)d_in[5];
    const float* a1_2 = (const float*)d_in[6];
    const float* a2_2 = (const float*)d_in[7];
    const float* b_2  = (const float*)d_in[8];
    const float* W2   = (const float*)d_in[9];             // [200,500]
    const float* bias2= (const float*)d_in[10];
    const float* a1_3 = (const float*)d_in[11];
    const float* a2_3 = (const float*)d_in[12];
    const float* b_3  = (const float*)d_in[13];
    const float* W3   = (const float*)d_in[14];            // [500,200]
    const float* bias3= (const float*)d_in[15];
    const float* a1_4 = (const float*)d_in[16];
    const float* a2_4 = (const float*)d_in[17];
    const float* b_4  = (const float*)d_in[18];
    const float* W4   = (const float*)d_in[19];            // [300,500]
    const float* bias4= (const float*)d_in[20];

    const int B = 64;

    // Workspace (53.76 MB): c1 = 9.6M floats, c2 = 3.84M floats.
    float* ws = (float*)d_ws;
    float* c1 = ws;                 // [B,T,500]; later filt_tmp [B,T,300]
    float* c2 = ws + 9600000;       // [B,T,200]

    // d_out regions double as scratch until the final transposes:
    // reg1 [0..5.76M): Wt1..4 (500K fl) + idx scratch, later final s4 [B,O,T]
    // reg2 [5.76M..11.52M): inputT / c4 / s4_tmp [B,T,300], later final filt
    float* out = (float*)d_out;
    float* reg1 = out;
    float* reg2 = out + 5760000;
    float* Wt1 = reg1;              // [300,500] = 150000
    float* Wt2 = reg1 + 150000;     // [500,200] = 100000
    float* Wt3 = reg1 + 250000;     // [200,500] = 100000
    float* Wt4 = reg1 + 350000;     // [500,300] = 150000
    uint8_t*  cnt8 = (uint8_t*)(reg1 + 500000);   // 16*64*320 B = 328 KB
    uint32_t* pk32 = (uint32_t*)(reg1 + 582000);  // 16*64*300*8 u32 = 9.8 MB
                                                  // ends at reg1+3,039,600

    const dim3 tb(32, 8);

    // Weight transposes W[O,K] -> Wt[K,O]
    transpose_rc<<<dim3(10, 16, 1), tb, 0, stream>>>(W1, Wt1, 500, 300);
    transpose_rc<<<dim3(16,  7, 1), tb, 0, stream>>>(W2, Wt2, 200, 500);
    transpose_rc<<<dim3( 7, 16, 1), tb, 0, stream>>>(W3, Wt3, 500, 200);
    transpose_rc<<<dim3(16, 10, 1), tb, 0, stream>>>(W4, Wt4, 300, 500);
    // Input spikes [B,IN,T] -> [B,T,IN]
    transpose_rc<<<dim3(10, 10, B), tb, 0, stream>>>(inputs, reg2, 300, 300);

    // Layer 1: 300 -> 500  (nkc = 10)
    build_idx<<<dim3(75, B), 256, 0, stream>>>(reg2, cnt8, pk32, 300, 10);
    spmm_idx<8><<<dim3(2, 10, B), 256, 0, stream>>>(Wt1, c1, cnt8, pk32, 300, 500, 10);
    lif_t<<<dim3(8, B), 64, 0, stream>>>(c1, bias1, a1_1, a2_1, b_1, 500);
    // Layer 2: 500 -> 200  (nkc = 16; 1 o-chunk -> RPW=4 for more blocks)
    build_idx<<<dim3(75, B), 256, 0, stream>>>(c1, cnt8, pk32, 500, 16);
    spmm_idx<4><<<dim3(1, 19, B), 256, 0, stream>>>(Wt2, c2, cnt8, pk32, 500, 200, 16);
    lif_t<<<dim3(4, B), 64, 0, stream>>>(c2, bias2, a1_2, a2_2, b_2, 200);
    // Layer 3: 200 -> 500  (nkc = 7)
    build_idx<<<dim3(75, B), 256, 0, stream>>>(c2, cnt8, pk32, 200, 7);
    spmm_idx<8><<<dim3(2, 10, B), 256, 0, stream>>>(Wt3, c1, cnt8, pk32, 200, 500, 7);
    lif_t<<<dim3(8, B), 64, 0, stream>>>(c1, bias3, a1_3, a2_3, b_3, 500);
    // Layer 4: 500 -> 300 into reg2 (inputT dead); fused LIF + output filter
    build_idx<<<dim3(75, B), 256, 0, stream>>>(c1, cnt8, pk32, 500, 16);
    spmm_idx<8><<<dim3(2, 10, B), 256, 0, stream>>>(Wt4, reg2, cnt8, pk32, 500, 300, 16);
    lif4_t<<<dim3(5, B), 64, 0, stream>>>(reg2, c1, bias4, a1_4, a2_4, b_4, 300);

    // Final transposes [B,T,O] -> [B,O,T]: s4 (overwrites Wt/idx), then filt.
    transpose_rc<<<dim3(10, 10, B), tb, 0, stream>>>(reg2, reg1, 300, 300);
    transpose_rc<<<dim3(10, 10, B), tb, 0, stream>>>(c1, reg2, 300, 300);
}

// Round 9
// 552.830 us; speedup vs baseline: 1.5888x; 1.5888x over previous
//
#include <hip/hip_runtime.h>
#include <stdint.h>

// ---- filter / neuron constants (double, matching the Python reference) ----
#define EMD 0.8824969025845955      // exp(-1/8)
#define ESD 0.6065306597126334      // exp(-1/2)
#define A1C ((float)(EMD + ESD))                    // y[t-1] coeff
#define A2C ((float)(-(EMD * ESD)))                 // y[t-2] coeff
#define BC  ((float)((8.0 / 6.0) * (EMD - ESD)))    // x[t] coeff (ETA=8/6)
#define EMF ((float)EMD)                            // reset decay

// B=64, T=300. Layers: 300 -> 500 -> 200 -> 500 -> 300.
//
// Exactness contract (absmax 0.0, rounds 1-8): reference currents are a
// SEQUENTIAL ascending-i fp32 fold of W[o,i]*s[i]; spikes are exactly 0/1.
// Skipping s==0 terms is bitwise-neutral; adds happen in ascending-i order.
// Pad indices read an all-zero LDS row: acc + (+0.0) is bitwise-identity.

// ---------------------------------------------------------------------------
// Generic batched transpose: src [Bt][R][C] -> dst [Bt][C][R]
// ---------------------------------------------------------------------------
__global__ __launch_bounds__(256) void transpose_rc(
    const float* __restrict__ src, float* __restrict__ dst, int R, int C)
{
    __shared__ float tile[32][33];
    const int c0 = blockIdx.x * 32;
    const int r0 = blockIdx.y * 32;
    const int b  = blockIdx.z;
    const float* S = src + (size_t)b * R * C;
    float* D = dst + (size_t)b * R * C;
    const int tx = threadIdx.x;      // 0..31
    const int ty = threadIdx.y;      // 0..7
#pragma unroll
    for (int s = 0; s < 4; s++) {
        const int r = r0 + ty + 8 * s;
        const int c = c0 + tx;
        if (r < R && c < C) tile[ty + 8 * s][tx] = S[(size_t)r * C + c];
    }
    __syncthreads();
#pragma unroll
    for (int s = 0; s < 4; s++) {
        const int c = c0 + ty + 8 * s;
        const int r = r0 + tx;
        if (c < C && r < R) D[(size_t)c * R + r] = tile[tx][ty + 8 * s];
    }
}

// ---------------------------------------------------------------------------
// build_idx (lane-parallel): per (b,t,kchunk of 32) pack ascending set-bit
// indices (+1) into 8 u32 (4/word, zero-padded) + group count ceil(n/4) u8.
// One wave per (b,t); each iteration covers 2 chunks (64 k's). Active lane
// scatters byte (pos+1) at its prefix rank into wave-private LDS; lanes 0-15
// read the u32 words back. NO serial ctz chain (round-8's 124 us bug).
// cnt8 layout: [kc][b][320]; pk32 layout: [kc][b][300][8].
// ---------------------------------------------------------------------------
__global__ __launch_bounds__(256) void build_idx(
    const float* __restrict__ Sp, uint8_t* __restrict__ cnt8,
    uint32_t* __restrict__ pk32, int K, int nkc)
{
    __shared__ uint32_t stage32[4][16];       // 64 B per wave, wave-private
    const int tid  = threadIdx.x;
    const int wv   = tid >> 6;
    const int lane = tid & 63;
    const int pos  = lane & 31;
    const int half = lane >> 5;               // which chunk of the pair
    const int b    = blockIdx.y;
    const int t    = blockIdx.x * 4 + wv;     // grid.x = 75 -> t < 300
    const float* row = Sp + ((size_t)b * 300 + t) * K;

    // preload all spike values (up to 16 chunks = 8 iters of 64)
    float sv[8];
#pragma unroll
    for (int i = 0; i < 8; i++) {
        const int k = i * 64 + lane;
        sv[i] = (i * 2 < nkc && k < K) ? row[k] : 0.0f;
    }

    volatile uint8_t*  sb  = (volatile uint8_t*)&stage32[wv][0];
    volatile uint32_t* sw  = (volatile uint32_t*)&stage32[wv][0];

    const int nit = (nkc + 1) >> 1;
    for (int i = 0; i < nit; i++) {
        const unsigned long long bal = __ballot(sv[i] != 0.0f);
        const uint32_t m32 = (uint32_t)(bal >> (half * 32));
        const int rank = __popc(m32 & ((1u << pos) - 1u));
        sb[lane] = 0;                                       // zero 64 B
        if (sv[i] != 0.0f) sb[half * 32 + rank] = (uint8_t)(pos + 1);
        // wave-private region + per-wave DS ordering -> no barrier needed
        if (lane < 16) {
            const int h   = lane >> 3;
            const int w   = lane & 7;
            const int kcc = i * 2 + h;
            if (kcc < nkc)
                pk32[(((size_t)kcc * 64 + b) * 300 + t) * 8 + w] =
                    sw[h * 8 + w];
        }
        if (pos == 0) {                                     // lanes 0 and 32
            const int kcc = i * 2 + half;
            if (kcc < nkc)
                cnt8[((size_t)kcc * 64 + b) * 320 + t] =
                    (uint8_t)((__popc(m32) + 3) >> 2);
        }
    }
}

// ---------------------------------------------------------------------------
// spmm_idx: C[b,t,o] = sum_{i in idx(b,t)} Wt[i,o]   (time-major, [B,T,O])
// Block: 256 thr (4 waves). Lane covers 4 o's (float4 / ds_read_b128).
// o-chunk 256, t-chunk 4*RPW (RPW t-rows per wave). K chunked at 32 rows in
// LDS (+ zero row 0 for pads); weights register-prefetched one chunk ahead.
// Indices/counts are wave-uniform -> scalar loads; no ballot/ctz in hot loop.
// ---------------------------------------------------------------------------
#define KG  32
#define OCN 256

template <int RPW>
__global__ __launch_bounds__(256) void spmm_idx(
    const float* __restrict__ Wt, float* __restrict__ C,
    const uint8_t* __restrict__ cnt8, const uint32_t* __restrict__ pk32,
    int K, int O, int nkc)
{
    __shared__ float Wls[(KG + 1) * OCN];   // row 0 = zeros; 33 KB
    const int tid  = threadIdx.x;
    const int lane = tid & 63;
    const int wvs  = __builtin_amdgcn_readfirstlane(tid >> 6);  // wave id, scalar
    const int oc   = blockIdx.x * OCN;
    const int t0   = blockIdx.y * (4 * RPW);
    const int b    = blockIdx.z;

    Wls[tid] = 0.0f;                        // zero row 0 (256 floats)

    const int scol  = lane * 4;             // 0..252
    const int srow0 = tid >> 6;             // 0..3

    float4 wpf[8];
#define LOADW(kc)                                                              \
    {                                                                          \
        const int kb_ = (kc) * KG;                                             \
        _Pragma("unroll")                                                      \
        for (int r = 0; r < 8; r++) {                                          \
            const int k = kb_ + srow0 + r * 4;                                 \
            float4 w = make_float4(0.f, 0.f, 0.f, 0.f);                        \
            if (k < K && oc + scol + 3 < O)                                    \
                w = *reinterpret_cast<const float4*>(&Wt[(size_t)k * O + oc + scol]); \
            wpf[r] = w;                                                        \
        }                                                                      \
    }
#define STOREW()                                                               \
    {                                                                          \
        _Pragma("unroll")                                                      \
        for (int r = 0; r < 8; r++)                                            \
            *reinterpret_cast<float4*>(&Wls[(size_t)(srow0 + r * 4 + 1) * OCN + scol]) = wpf[r]; \
    }

    float4 acc[RPW];
#pragma unroll
    for (int u = 0; u < RPW; u++) acc[u] = make_float4(0.f, 0.f, 0.f, 0.f);

    LOADW(0)
    STOREW()
    __syncthreads();

    const float* lrow = Wls + lane * 4;     // + idx*256 floats selects the row

    for (int kc = 0; kc < nkc; kc++) {
        if (kc + 1 < nkc) LOADW(kc + 1)     // overlaps the index loops below
        const uint32_t* c32 =
            (const uint32_t*)(cnt8 + ((size_t)kc * 64 + b) * 320 + t0);
        const uint32_t* pbase = pk32 + ((size_t)kc * 64 + b) * 300 * 8;
#pragma unroll
        for (int u = 0; u < RPW; u++) {
            const int ts = t0 + u * 4 + wvs;
            int ng = (int)((c32[u] >> (wvs * 8)) & 0xffu);
            if (ts >= 300) ng = 0;          // tail t-chunk: poison guard
            const uint32_t* prow = pbase + (size_t)ts * 8;
            float4 a = acc[u];
            for (int g = 0; g < ng; g++) {
                const uint32_t pw = prow[g];
                const int f0 = (int)((pw      ) & 0xffu) << 8;
                const int f1 = (int)((pw >> 8) & 0xffu) << 8;
                const int f2 = (int)((pw >> 16) & 0xffu) << 8;
                const int f3 = (int)((pw >> 24)        ) << 8;
                const float4 w0 = *reinterpret_cast<const float4*>(lrow + f0);
                const float4 w1 = *reinterpret_cast<const float4*>(lrow + f1);
                const float4 w2 = *reinterpret_cast<const float4*>(lrow + f2);
                const float4 w3 = *reinterpret_cast<const float4*>(lrow + f3);
                a.x += w0.x; a.y += w0.y; a.z += w0.z; a.w += w0.w;
                a.x += w1.x; a.y += w1.y; a.z += w1.z; a.w += w1.w;
                a.x += w2.x; a.y += w2.y; a.z += w2.z; a.w += w2.w;
                a.x += w3.x; a.y += w3.y; a.z += w3.z; a.w += w3.w;
            }
            acc[u] = a;
        }
        if (kc + 1 < nkc) {
            __syncthreads();
            STOREW()
            __syncthreads();
        }
    }

    float* Cb = C + (size_t)b * 300 * O;
#pragma unroll
    for (int u = 0; u < RPW; u++) {
        const int t = t0 + u * 4 + wvs;
        const int o = oc + lane * 4;
        if (t < 300 && o + 3 < O)           // O%4==0 -> all-or-nothing
            *reinterpret_cast<float4*>(&Cb[(size_t)t * O + o]) = acc[u];
    }
}

// ---------------------------------------------------------------------------
// LIF in time-major layout, in-place: C[b,t,o] currents -> spikes.
// One thread per (b,o); strided column walk, 8-deep unrolled prefetch ring.
// ---------------------------------------------------------------------------
#define LIF_STEP_S(xval, sval)                                                 \
    {                                                                          \
        const float y = A1 * y1 + A2 * y2 + Bc * (xval); y2 = y1; y1 = y;      \
        const float v = y + bi + r;                                            \
        sval = (v >= 1.0f) ? 1.0f : 0.0f;                                      \
        r = r * EMF - sval;                                                    \
    }

__global__ __launch_bounds__(64) void lif_t(
    float* __restrict__ C, const float* __restrict__ bias,
    const float* __restrict__ a1p, const float* __restrict__ a2p,
    const float* __restrict__ bp, int O)
{
    const int o = blockIdx.x * 64 + threadIdx.x;
    const int b = blockIdx.y;
    if (o >= O) return;
    const float A1 = a1p[0], A2 = a2p[0], Bc = bp[0];
    const float bi = bias[o];
    float* col = C + (size_t)b * 300 * O + o;

    float pf[8];
#pragma unroll
    for (int u = 0; u < 8; u++) pf[u] = col[(size_t)u * O];

    float y1 = 0.f, y2 = 0.f, r = 0.f;
    for (int blk = 0; blk < 37; blk++) {       // t = 0..295
#pragma unroll
        for (int u = 0; u < 8; u++) {
            const int t = blk * 8 + u;
            const float x = pf[u];
            if (t + 8 < 300) pf[u] = col[(size_t)(t + 8) * O];
            float s;
            LIF_STEP_S(x, s)
            col[(size_t)t * O] = s;
        }
    }
#pragma unroll
    for (int u = 0; u < 4; u++) {              // t = 296..299
        const float x = pf[u];
        float s;
        LIF_STEP_S(x, s)
        col[(size_t)(296 + u) * O] = s;
    }
}

// ---------------------------------------------------------------------------
// Layer-4 LIF + fixed output dual-exp IIR. C: currents->spikes (in place),
// F: filtered output. Both [B,T,O], O=300.
// ---------------------------------------------------------------------------
__global__ __launch_bounds__(64) void lif4_t(
    float* __restrict__ C, float* __restrict__ F,
    const float* __restrict__ bias,
    const float* __restrict__ a1p, const float* __restrict__ a2p,
    const float* __restrict__ bp, int O)
{
    const int o = blockIdx.x * 64 + threadIdx.x;
    const int b = blockIdx.y;
    if (o >= O) return;
    const float A1 = a1p[0], A2 = a2p[0], Bc = bp[0];
    const float bi = bias[o];
    float* col  = C + (size_t)b * 300 * O + o;
    float* fcol = F + (size_t)b * 300 * O + o;

    float pf[8];
#pragma unroll
    for (int u = 0; u < 8; u++) pf[u] = col[(size_t)u * O];

    float y1 = 0.f, y2 = 0.f, r = 0.f;
    float z1 = 0.f, z2 = 0.f;
    for (int blk = 0; blk < 37; blk++) {
#pragma unroll
        for (int u = 0; u < 8; u++) {
            const int t = blk * 8 + u;
            const float x = pf[u];
            if (t + 8 < 300) pf[u] = col[(size_t)(t + 8) * O];
            float s;
            LIF_STEP_S(x, s)
            const float z = A1C * z1 + A2C * z2 + BC * s; z2 = z1; z1 = z;
            col[(size_t)t * O]  = s;
            fcol[(size_t)t * O] = z;
        }
    }
#pragma unroll
    for (int u = 0; u < 4; u++) {
        const int t = 296 + u;
        const float x = pf[u];
        float s;
        LIF_STEP_S(x, s)
        const float z = A1C * z1 + A2C * z2 + BC * s; z2 = z1; z1 = z;
        col[(size_t)t * O]  = s;
        fcol[(size_t)t * O] = z;
    }
}

// ---------------------------------------------------------------------------
extern "C" void kernel_launch(void* const* d_in, const int* in_sizes, int n_in,
                              void* d_out, int out_size, void* d_ws, size_t ws_size,
                              hipStream_t stream)
{
    const float* inputs = (const float*)d_in[0];           // [64,300,300] binary
    const float* a1_1 = (const float*)d_in[1];
    const float* a2_1 = (const float*)d_in[2];
    const float* b_1  = (const float*)d_in[3];
    const float* W1   = (const float*)d_in[4];             // [500,300]
    const float* bias1= (const float*)d_in[5];
    const float* a1_2 = (const float*)d_in[6];
    const float* a2_2 = (const float*)d_in[7];
    const float* b_2  = (const float*)d_in[8];
    const float* W2   = (const float*)d_in[9];             // [200,500]
    const float* bias2= (const float*)d_in[10];
    const float* a1_3 = (const float*)d_in[11];
    const float* a2_3 = (const float*)d_in[12];
    const float* b_3  = (const float*)d_in[13];
    const float* W3   = (const float*)d_in[14];            // [500,200]
    const float* bias3= (const float*)d_in[15];
    const float* a1_4 = (const float*)d_in[16];
    const float* a2_4 = (const float*)d_in[17];
    const float* b_4  = (const float*)d_in[18];
    const float* W4   = (const float*)d_in[19];            // [300,500]
    const float* bias4= (const float*)d_in[20];

    const int B = 64;

    // Workspace (53.76 MB): c1 = 9.6M floats, c2 = 3.84M floats.
    float* ws = (float*)d_ws;
    float* c1 = ws;                 // [B,T,500]; later filt_tmp [B,T,300]
    float* c2 = ws + 9600000;       // [B,T,200]

    // d_out regions double as scratch until the final transposes:
    // reg1 [0..5.76M): Wt1..4 (500K fl) + idx scratch, later final s4 [B,O,T]
    // reg2 [5.76M..11.52M): inputT / c4 / s4_tmp [B,T,300], later final filt
    float* out = (float*)d_out;
    float* reg1 = out;
    float* reg2 = out + 5760000;
    float* Wt1 = reg1;              // [300,500] = 150000
    float* Wt2 = reg1 + 150000;     // [500,200] = 100000
    float* Wt3 = reg1 + 250000;     // [200,500] = 100000
    float* Wt4 = reg1 + 350000;     // [500,300] = 150000
    uint8_t*  cnt8 = (uint8_t*)(reg1 + 500000);   // 16*64*320 B = 328 KB
    uint32_t* pk32 = (uint32_t*)(reg1 + 582000);  // 16*64*300*8 u32 = 9.8 MB
                                                  // ends at reg1+3,039,600

    const dim3 tb(32, 8);

    // Weight transposes W[O,K] -> Wt[K,O]
    transpose_rc<<<dim3(10, 16, 1), tb, 0, stream>>>(W1, Wt1, 500, 300);
    transpose_rc<<<dim3(16,  7, 1), tb, 0, stream>>>(W2, Wt2, 200, 500);
    transpose_rc<<<dim3( 7, 16, 1), tb, 0, stream>>>(W3, Wt3, 500, 200);
    transpose_rc<<<dim3(16, 10, 1), tb, 0, stream>>>(W4, Wt4, 300, 500);
    // Input spikes [B,IN,T] -> [B,T,IN]
    transpose_rc<<<dim3(10, 10, B), tb, 0, stream>>>(inputs, reg2, 300, 300);

    // Layer 1: 300 -> 500  (nkc = 10)
    build_idx<<<dim3(75, B), 256, 0, stream>>>(reg2, cnt8, pk32, 300, 10);
    spmm_idx<8><<<dim3(2, 10, B), 256, 0, stream>>>(Wt1, c1, cnt8, pk32, 300, 500, 10);
    lif_t<<<dim3(8, B), 64, 0, stream>>>(c1, bias1, a1_1, a2_1, b_1, 500);
    // Layer 2: 500 -> 200  (nkc = 16; 1 o-chunk -> RPW=4 for more blocks)
    build_idx<<<dim3(75, B), 256, 0, stream>>>(c1, cnt8, pk32, 500, 16);
    spmm_idx<4><<<dim3(1, 19, B), 256, 0, stream>>>(Wt2, c2, cnt8, pk32, 500, 200, 16);
    lif_t<<<dim3(4, B), 64, 0, stream>>>(c2, bias2, a1_2, a2_2, b_2, 200);
    // Layer 3: 200 -> 500  (nkc = 7)
    build_idx<<<dim3(75, B), 256, 0, stream>>>(c2, cnt8, pk32, 200, 7);
    spmm_idx<8><<<dim3(2, 10, B), 256, 0, stream>>>(Wt3, c1, cnt8, pk32, 200, 500, 7);
    lif_t<<<dim3(8, B), 64, 0, stream>>>(c1, bias3, a1_3, a2_3, b_3, 500);
    // Layer 4: 500 -> 300 into reg2 (inputT dead); fused LIF + output filter
    build_idx<<<dim3(75, B), 256, 0, stream>>>(c1, cnt8, pk32, 500, 16);
    spmm_idx<8><<<dim3(2, 10, B), 256, 0, stream>>>(Wt4, reg2, cnt8, pk32, 500, 300, 16);
    lif4_t<<<dim3(5, B), 64, 0, stream>>>(reg2, c1, bias4, a1_4, a2_4, b_4, 300);

    // Final transposes [B,T,O] -> [B,O,T]: s4 (overwrites Wt/idx), then filt.
    transpose_rc<<<dim3(10, 10, B), tb, 0, stream>>>(reg2, reg1, 300, 300);
    transpose_rc<<<dim3(10, 10, B), tb, 0, stream>>>(c1, reg2, 300, 300);
}